// Round 1
// baseline (258.244 us; speedup 1.0000x reference)
//
#include <hip/hip_runtime.h>

// Problem constants (B=2, C=64, H=W=192, EXP=4, DG=4, K=3)
#define BN   2
#define CN   64
#define HN   192
#define WN   192
#define HWN  36864          // 192*192
#define OCN  256            // EXP*C
#define JCN  72             // DG*2*9

// fused deform+final tile geometry: 4x16 pixel tile, all 64 channels
#define TR   4              // tile rows
#define TC   16             // tile cols
#define TPX  64             // TR*TC pixels per block
#define GH   13             // staged x rows: 4 halo top + TR + 5 bottom (incl +1)
#define GW   26             // staged x cols: 4 halo left + TC + 6 right (incl +1)
#define GSZ  (GH * GW)      // 338

typedef __attribute__((ext_vector_type(8))) short bf16x8;
typedef __attribute__((ext_vector_type(4))) float f32x4;
typedef __attribute__((ext_vector_type(4))) unsigned short u16x4;

__device__ __forceinline__ unsigned short f2bf(float f) {
    union { float f; unsigned u; } v; v.f = f;
    unsigned r = v.u + 0x7fffu + ((v.u >> 16) & 1u);
    return (unsigned short)(r >> 16);
}

// ---------------------------------------------------------------------------
// Prep:
//  job 1: w2mf = w2 (72x256) bf16, MFMA A-frag order (tm=0..4, s=0..7)
//  job 2: w_outmf = w_out (64x64) bf16, MFMA A-frag order (tm=0..3, s=0..1)
//  job 3: w1p[o*8+kk] = w1[o*9+k(kk)], k skips center.
// ---------------------------------------------------------------------------
__global__ __launch_bounds__(256) void k_prep(const float* __restrict__ w2,
                                              const float* __restrict__ w_out,
                                              const float* __restrict__ w1,
                                              unsigned short* __restrict__ w2mf,
                                              unsigned short* __restrict__ w_outmf,
                                              float* __restrict__ w1p) {
    int idx = blockIdx.x * 256 + threadIdx.x;
    if (idx < 20480) {
        int j  = idx & 7;
        int l  = (idx >> 3) & 63;
        int ts = idx >> 9;             // tm*8+s, 0..39
        int tm = ts >> 3, s = ts & 7;
        int jrow = tm * 16 + (l & 15);
        int k    = s * 32 + (l >> 4) * 8 + j;
        float v = (jrow < JCN) ? w2[jrow * OCN + k] : 0.f;
        w2mf[idx] = f2bf(v);
    } else if (idx < 24576) {
        int r  = idx - 20480;          // 0..4095
        int j  = r & 7;
        int l  = (r >> 3) & 63;
        int ts = r >> 9;               // tm*2+s, 0..7
        int tm = ts >> 1, s = ts & 1;
        int m  = tm * 16 + (l & 15);
        int k  = s * 32 + (l >> 4) * 8 + j;
        w_outmf[r] = f2bf(w_out[m * CN + k]);
    } else if (idx < 26624) {
        int r = idx - 24576;           // 0..2047
        int o = r >> 3, kk = r & 7;
        int k = kk < 4 ? kk : kk + 1;
        w1p[r] = w1[o * 9 + k];
    }
}

// ---------------------------------------------------------------------------
// K1: offsets t + fused x1 copy.  (unchanged — 53 us, to attack next round)
// ---------------------------------------------------------------------------
__global__ __launch_bounds__(256, 4) void k_offsets(const float* __restrict__ x,
                                                    const float* __restrict__ w1p,
                                                    const unsigned short* __restrict__ w2mf,
                                                    const float* __restrict__ b2,
                                                    float* __restrict__ t_out,
                                                    float* __restrict__ x_copy) {
    const int tid  = threadIdx.x;
    const int wv   = tid >> 6;
    const int lane = tid & 63;
    const int q    = lane >> 4;
    const int n    = lane & 15;
    const int n0   = blockIdx.x * 64 + wv * 16;
    const int y    = blockIdx.y;
    const int b    = blockIdx.z;
    const int xcol = n0 + n;
    const float* xb = x + (size_t)b * CN * HWN;

    auto load_chunk = [&](int s, float (*ld)[9]) {
        #pragma unroll
        for (int cc = 0; cc < 2; ++cc) {
            int c = 8 * s + 2 * q + cc;
            const float* xp = xb + (size_t)c * HWN;
            #pragma unroll
            for (int k = 0; k < 9; ++k) {
                int ky = k / 3, kx = k - 3 * ky;
                int yy = y - 1 + ky, xx = xcol - 1 + kx;
                float v = 0.f;
                if ((unsigned)yy < (unsigned)HN && (unsigned)xx < (unsigned)WN)
                    v = xp[yy * WN + xx];
                ld[cc][k] = v;
            }
        }
    };

    f32x4 acc[5];
    #pragma unroll
    for (int t = 0; t < 5; ++t) acc[t] = (f32x4){0.f, 0.f, 0.f, 0.f};

    const bf16x8* ap = (const bf16x8*)w2mf + lane;

    float lbuf[2][2][9];
    load_chunk(0, lbuf[0]);
    #pragma unroll
    for (int s = 0; s < 8; ++s) {
        if (s < 7) load_chunk(s + 1, lbuf[(s + 1) & 1]);
        float (*ld)[9] = lbuf[s & 1];

        float dd[2][8];
        #pragma unroll
        for (int cc = 0; cc < 2; ++cc) {
            int c = 8 * s + 2 * q + cc;
            float ctr = ld[cc][4];
            x_copy[((size_t)b * CN + c) * HWN + y * WN + xcol] = ctr;
            #pragma unroll
            for (int kk = 0; kk < 8; ++kk) {
                int k = kk < 4 ? kk : kk + 1;
                dd[cc][kk] = ld[cc][k] - ctr;
            }
        }

        bf16x8 bfr;
        const float4* wp = (const float4*)(w1p + (size_t)(s * 32 + q * 8) * 8);
        #pragma unroll
        for (int j = 0; j < 8; ++j) {
            float4 wa = wp[2 * j];
            float4 wb = wp[2 * j + 1];
            const float* d = dd[j >> 2];
            float a = wa.x * d[0] + wa.y * d[1] + wa.z * d[2] + wa.w * d[3]
                    + wb.x * d[4] + wb.y * d[5] + wb.z * d[6] + wb.w * d[7];
            bfr[j] = (short)f2bf(a);
        }

        #pragma unroll
        for (int tm = 0; tm < 5; ++tm) {
            bf16x8 af = ap[(tm * 8 + s) * 64];
            acc[tm] = __builtin_amdgcn_mfma_f32_16x16x32_bf16(af, bfr, acc[tm], 0, 0, 0);
        }
    }

    float* tb = t_out + (size_t)b * JCN * HWN + y * WN + n0 + n;
    #pragma unroll
    for (int tm = 0; tm < 5; ++tm) {
        #pragma unroll
        for (int r = 0; r < 4; ++r) {
            int j = tm * 16 + q * 4 + r;
            if (j < JCN)
                tb[(size_t)j * HWN] = acc[tm][r] + b2[j];
        }
    }
}

// ---------------------------------------------------------------------------
// K2 (fused): depthwise deformable conv + wsum correction + 1x1 out-conv.
// Block = 4x16 pixel tile, ALL 64 channels, 4 group-passes of 16 channels.
// y never goes to HBM: packed bf16 into LDS, consumed by MFMA epilogue.
// ---------------------------------------------------------------------------
__device__ __forceinline__ float dsample(const float* __restrict__ p, int yi, int xi) {
    if ((unsigned)yi < (unsigned)HN && (unsigned)xi < (unsigned)WN)
        return p[yi * WN + xi];
    return 0.f;
}

__global__ __launch_bounds__(256, 4) void k_def_final(const float* __restrict__ x,
                                                      const float* __restrict__ t_in,
                                                      const float* __restrict__ wdef,
                                                      const unsigned short* __restrict__ womf,
                                                      float* __restrict__ m_out) {
    __shared__ float xs[16 * GSZ];              // 21632 B: 16ch x 13 x 26 window
    __shared__ unsigned short ybuf[TPX * 72];   //  9216 B: [px][64c + 8 pad], 144B rows
    __shared__ float wks[9 * 64];               //  2304 B: [k][c]
    __shared__ float wsums[64];                 //   256 B

    const int tid = threadIdx.x;
    const int x0  = blockIdx.x * TC;
    const int yr0 = blockIdx.y * TR;
    const int b   = blockIdx.z;
    const int p   = tid & 63;                   // pixel within tile (deform phase)
    const int cp  = tid >> 6;                   // channel sub-group 0..3
    const int rr  = p >> 4;                     // tile row
    const int cc  = p & 15;                     // tile col
    const int row_lo = yr0 - 4;
    const int col_lo = x0 - 4;
    const float* xb = x + (size_t)b * CN * HWN;

    // stage deform weights (tiny, L2)
    for (int i = tid; i < 576; i += 256)
        wks[i] = wdef[(i & 63) * 9 + (i >> 6)];
    if (tid < 64) {
        float s = 0.f;
        #pragma unroll
        for (int k = 0; k < 9; ++k) s += wdef[tid * 9 + k];
        wsums[tid] = s;
    }

    const int sch = tid >> 4;                   // staging: channel 0..15
    const int sc  = tid & 15;                   // staging: col lane
    const float ry_basef = (float)(yr0 + rr - 1);
    const float rx_basef = (float)(x0 + cc - 1);

    for (int g = 0; g < 4; ++g) {
        // prefetch this thread's 18 offsets for group g (coalesced, issued early)
        float dyr[9], dxr[9];
        {
            const float* tbp = t_in + ((size_t)b * JCN + g * 18) * HWN
                             + (yr0 + rr) * WN + x0 + cc;
            #pragma unroll
            for (int k = 0; k < 9; ++k) {
                dyr[k] = tbp[(size_t)(2 * k) * HWN];
                dxr[k] = tbp[(size_t)(2 * k + 1) * HWN];
            }
        }

        // stage x window for channels g*16 .. g*16+15 (zero-filled outside)
        {
            const float* xp = xb + (size_t)(g * 16 + sch) * HWN;
            float* xd = xs + sch * GSZ;
            for (int r2 = 0; r2 < GH; ++r2) {
                int yy = row_lo + r2;
                bool yok = (unsigned)yy < (unsigned)HN;
                int rowoff = yy * WN;
                #pragma unroll
                for (int h = 0; h < 2; ++h) {
                    int c2 = sc + h * 16;
                    if (c2 < GW) {
                        int xx = col_lo + c2;
                        float v = 0.f;
                        if (yok && (unsigned)xx < (unsigned)WN)
                            v = xp[rowoff + xx];
                        xd[r2 * GW + c2] = v;
                    }
                }
            }
        }
        __syncthreads();

        // deform for 4 channels: c = g*16 + cp*4 + {0..3}
        const int cbase = g * 16 + cp * 4;
        float acc[4];
        {
            f32x4 ws4 = *(const f32x4*)&wsums[cbase];
            const float* ctr = xs + (cp * 4) * GSZ + (rr + 4) * GW + (cc + 4);
            #pragma unroll
            for (int i = 0; i < 4; ++i)
                acc[i] = -ctr[i * GSZ] * ws4[i];
        }

        #pragma unroll
        for (int k = 0; k < 9; ++k) {
            const int ky = k / 3, kx = k - 3 * ky;
            float py  = ry_basef + (float)ky + dyr[k];
            float pxf = rx_basef + (float)kx + dxr[k];
            float y0f = floorf(py), x0f = floorf(pxf);
            float wy = py - y0f, wx = pxf - x0f;
            int yi = (int)y0f, xi = (int)x0f;
            int ry = yi - row_lo, rx = xi - col_lo;
            float omwy = 1.f - wy, omwx = 1.f - wx;
            float w00 = omwy * omwx;
            float w01 = omwy * wx;
            float w10 = wy * omwx;
            float w11 = wy * wx;
            f32x4 wk4 = *(const f32x4*)&wks[k * 64 + cbase];
            if ((unsigned)ry < (GH - 1) && (unsigned)rx < (GW - 1)) {
                const float* p0 = xs + (cp * 4) * GSZ + ry * GW + rx;
                #pragma unroll
                for (int i = 0; i < 4; ++i) {
                    const float* pp = p0 + i * GSZ;
                    float bil = pp[0] * w00 + pp[1] * w01 + pp[GW] * w10 + pp[GW + 1] * w11;
                    acc[i] += wk4[i] * bil;
                }
            } else {
                #pragma unroll
                for (int i = 0; i < 4; ++i) {
                    const float* xp = xb + (size_t)(cbase + i) * HWN;
                    float v00 = dsample(xp, yi,     xi);
                    float v01 = dsample(xp, yi,     xi + 1);
                    float v10 = dsample(xp, yi + 1, xi);
                    float v11 = dsample(xp, yi + 1, xi + 1);
                    float bil = v00 * w00 + v01 * w01 + v10 * w10 + v11 * w11;
                    acc[i] += wk4[i] * bil;
                }
            }
        }

        // pack 4 channels of y to bf16 into ybuf[p][cbase..cbase+3]
        u16x4 pk;
        #pragma unroll
        for (int i = 0; i < 4; ++i) pk[i] = f2bf(acc[i]);
        *(u16x4*)&ybuf[p * 72 + cbase] = pk;
        __syncthreads();
    }

    // ---- MFMA epilogue: m = w_out . y ----
    // wave wv owns pixels wv*16 + n (row rr=wv, col n); B-frag per k_final layout.
    const int lane = tid & 63;
    const int q    = lane >> 4;
    const int n    = lane & 15;
    const int wv   = tid >> 6;

    const unsigned short* yrow = &ybuf[(wv * 16 + n) * 72];
    bf16x8 bfr0 = *(const bf16x8*)&yrow[q * 8];
    bf16x8 bfr1 = *(const bf16x8*)&yrow[32 + q * 8];

    const bf16x8* ap = (const bf16x8*)womf + lane;
    f32x4 mc[4];
    #pragma unroll
    for (int tm = 0; tm < 4; ++tm) mc[tm] = (f32x4){0.f, 0.f, 0.f, 0.f};
    #pragma unroll
    for (int tm = 0; tm < 4; ++tm) {
        mc[tm] = __builtin_amdgcn_mfma_f32_16x16x32_bf16(ap[(tm * 2 + 0) * 64], bfr0, mc[tm], 0, 0, 0);
        mc[tm] = __builtin_amdgcn_mfma_f32_16x16x32_bf16(ap[(tm * 2 + 1) * 64], bfr1, mc[tm], 0, 0, 0);
    }

    // D layout: col=lane&15, row=q*4+reg ; o = tm*16 + q*4 + r
    float* mb = m_out + (size_t)b * CN * HWN + (size_t)(yr0 + wv) * WN + x0 + n;
    #pragma unroll
    for (int tm = 0; tm < 4; ++tm) {
        #pragma unroll
        for (int r = 0; r < 4; ++r)
            mb[(size_t)(tm * 16 + q * 4 + r) * HWN] = mc[tm][r];
    }
}

// ---------------------------------------------------------------------------
extern "C" void kernel_launch(void* const* d_in, const int* in_sizes, int n_in,
                              void* d_out, int out_size, void* d_ws, size_t ws_size,
                              hipStream_t stream) {
    const float* x1    = (const float*)d_in[0];   // 2*64*192*192
    const float* w_off1 = (const float*)d_in[1];  // 256*9
    const float* w_off2 = (const float*)d_in[2];  // 72*256
    const float* b_off2 = (const float*)d_in[3];  // 72
    const float* w_def = (const float*)d_in[4];   // 64*9
    const float* w_out = (const float*)d_in[5];   // 64*64

    float* out = (float*)d_out;
    const size_t n_x = (size_t)BN * CN * HWN;     // 4718592
    float* out_x1 = out;                          // output 0: x1 copy (fused into k_offsets)
    float* out_m  = out + n_x;                    // output 1: m

    // Workspace layout (bytes)
    char* ws0 = (char*)d_ws;
    unsigned short* w2mf   = (unsigned short*)ws0;            // 20480 bf16 = 40960 B
    unsigned short* w_outmf = (unsigned short*)(ws0 + 40960); // 4096 bf16 = 8192 B
    float* w1p    = (float*)(ws0 + 49152);                    // 2048 f = 8192 B
    float* t_ws   = (float*)(ws0 + 57344);                    // 2*72*36864 f

    dim3 blk(256);

    k_prep<<<dim3(104), blk, 0, stream>>>(w_off2, w_out, w_off1, w2mf, w_outmf, w1p);
    k_offsets<<<dim3(WN / 64, HN, BN), blk, 0, stream>>>(x1, w1p, w2mf, b_off2,
                                                         t_ws, out_x1);
    k_def_final<<<dim3(WN / TC, HN / TR, BN), blk, 0, stream>>>(x1, t_ws, w_def,
                                                                w_outmf, out_m);
}

// Round 2
// 170.107 us; speedup vs baseline: 1.5181x; 1.5181x over previous
//
#include <hip/hip_runtime.h>

// Problem constants (B=2, C=64, H=W=192, EXP=4, DG=4, K=3)
#define BN   2
#define CN   64
#define HN   192
#define WN   192
#define HWN  36864          // 192*192
#define OCN  256            // EXP*C
#define JCN  72             // DG*2*9
#define SN   32             // pixel strip for deform

// k_deform tile geometry
#define DROWS 8             // output rows per block
#define XH    17            // staged x rows
#define XW    42            // staged x cols
#define XRT   4             // row halo top
#define XCL   4             // col halo left

#define PGRPS 2304          // HWN/16 pixel-groups per image

typedef __attribute__((ext_vector_type(8))) short bf16x8;
typedef __attribute__((ext_vector_type(8))) unsigned short u16x8;
typedef __attribute__((ext_vector_type(4))) float f32x4;

__device__ __forceinline__ unsigned short f2bf(float f) {
    union { float f; unsigned u; } v; v.f = f;
    unsigned r = v.u + 0x7fffu + ((v.u >> 16) & 1u);
    return (unsigned short)(r >> 16);
}

// ---------------------------------------------------------------------------
// Prep:
//  job 1: w2mf = w2 (72x256) bf16, MFMA A-frag order (tm=0..4, s=0..7)
//  job 2: w_outmf = w_out (64x64) bf16, MFMA A-frag order (tm=0..3, s=0..1)
//  job 3: w1p[o*8+kk] = w1[o*9+k(kk)], k skips center.
// ---------------------------------------------------------------------------
__global__ __launch_bounds__(256) void k_prep(const float* __restrict__ w2,
                                              const float* __restrict__ w_out,
                                              const float* __restrict__ w1,
                                              unsigned short* __restrict__ w2mf,
                                              unsigned short* __restrict__ w_outmf,
                                              float* __restrict__ w1p) {
    int idx = blockIdx.x * 256 + threadIdx.x;
    if (idx < 20480) {
        int j  = idx & 7;
        int l  = (idx >> 3) & 63;
        int ts = idx >> 9;             // tm*8+s, 0..39
        int tm = ts >> 3, s = ts & 7;
        int jrow = tm * 16 + (l & 15);
        int k    = s * 32 + (l >> 4) * 8 + j;
        float v = (jrow < JCN) ? w2[jrow * OCN + k] : 0.f;
        w2mf[idx] = f2bf(v);
    } else if (idx < 24576) {
        int r  = idx - 20480;          // 0..4095
        int j  = r & 7;
        int l  = (r >> 3) & 63;
        int ts = r >> 9;               // tm*2+s, 0..7
        int tm = ts >> 1, s = ts & 1;
        int m  = tm * 16 + (l & 15);
        int k  = s * 32 + (l >> 4) * 8 + j;
        w_outmf[r] = f2bf(w_out[m * CN + k]);
    } else if (idx < 26624) {
        int r = idx - 24576;           // 0..2047
        int o = r >> 3, kk = r & 7;
        int k = kk < 4 ? kk : kk + 1;
        w1p[r] = w1[o * 9 + k];
    }
}

// ---------------------------------------------------------------------------
// K1: offsets t + fused x1 copy.  Fused MFMA, no LDS/barriers, prefetch
// distance 1.  NOTE: distance-2 (lbuf[3]) spills at the ~64-VGPR budget the
// compiler targets under (256,4) — keep lbuf[2].
// NEW: bijective XCD-chunked block swizzle (1152 = 8*144) so each XCD owns a
// contiguous 48-row band -> 3x3-halo row re-reads become L2 hits.
// ---------------------------------------------------------------------------
__global__ __launch_bounds__(256, 4) void k_offsets(const float* __restrict__ x,
                                                    const float* __restrict__ w1p,
                                                    const unsigned short* __restrict__ w2mf,
                                                    const float* __restrict__ b2,
                                                    float* __restrict__ t_out,
                                                    float* __restrict__ x_copy) {
    // swizzle: orig flat id f, XCD = f%8 (round-robin); give XCD k slots
    // [144k, 144k+144) -> contiguous y-band of 48 rows per XCD.
    const int f  = blockIdx.x + 3 * blockIdx.y + 576 * blockIdx.z;
    const int nn = (f & 7) * 144 + (f >> 3);
    const int bx = nn % 3;
    const int by = (nn / 3) % 192;
    const int bz = nn / 576;

    const int tid  = threadIdx.x;
    const int wv   = tid >> 6;
    const int lane = tid & 63;
    const int q    = lane >> 4;
    const int n    = lane & 15;
    const int n0   = bx * 64 + wv * 16;
    const int y    = by;
    const int b    = bz;
    const int xcol = n0 + n;
    const float* xb = x + (size_t)b * CN * HWN;

    auto load_chunk = [&](int s, float (*ld)[9]) {
        #pragma unroll
        for (int cc = 0; cc < 2; ++cc) {
            int c = 8 * s + 2 * q + cc;
            const float* xp = xb + (size_t)c * HWN;
            #pragma unroll
            for (int k = 0; k < 9; ++k) {
                int ky = k / 3, kx = k - 3 * ky;
                int yy = y - 1 + ky, xx = xcol - 1 + kx;
                float v = 0.f;
                if ((unsigned)yy < (unsigned)HN && (unsigned)xx < (unsigned)WN)
                    v = xp[yy * WN + xx];
                ld[cc][k] = v;
            }
        }
    };

    f32x4 acc[5];
    #pragma unroll
    for (int t = 0; t < 5; ++t) acc[t] = (f32x4){0.f, 0.f, 0.f, 0.f};

    const bf16x8* ap = (const bf16x8*)w2mf + lane;

    float lbuf[2][2][9];
    load_chunk(0, lbuf[0]);
    #pragma unroll
    for (int s = 0; s < 8; ++s) {
        if (s < 7) load_chunk(s + 1, lbuf[(s + 1) & 1]);
        float (*ld)[9] = lbuf[s & 1];

        float dd[2][8];
        #pragma unroll
        for (int cc = 0; cc < 2; ++cc) {
            int c = 8 * s + 2 * q + cc;
            float ctr = ld[cc][4];
            x_copy[((size_t)b * CN + c) * HWN + y * WN + xcol] = ctr;
            #pragma unroll
            for (int kk = 0; kk < 8; ++kk) {
                int k = kk < 4 ? kk : kk + 1;
                dd[cc][kk] = ld[cc][k] - ctr;
            }
        }

        bf16x8 bfr;
        const float4* wp = (const float4*)(w1p + (size_t)(s * 32 + q * 8) * 8);
        #pragma unroll
        for (int j = 0; j < 8; ++j) {
            float4 wa = wp[2 * j];
            float4 wb = wp[2 * j + 1];
            const float* d = dd[j >> 2];
            float a = wa.x * d[0] + wa.y * d[1] + wa.z * d[2] + wa.w * d[3]
                    + wb.x * d[4] + wb.y * d[5] + wb.z * d[6] + wb.w * d[7];
            bfr[j] = (short)f2bf(a);
        }

        #pragma unroll
        for (int tm = 0; tm < 5; ++tm) {
            bf16x8 af = ap[(tm * 8 + s) * 64];
            acc[tm] = __builtin_amdgcn_mfma_f32_16x16x32_bf16(af, bfr, acc[tm], 0, 0, 0);
        }
    }

    // Epilogue (D layout: col=lane&15, row=q*4+reg)
    float* tb = t_out + (size_t)b * JCN * HWN + y * WN + n0 + n;
    #pragma unroll
    for (int tm = 0; tm < 5; ++tm) {
        #pragma unroll
        for (int r = 0; r < 4; ++r) {
            int j = tm * 16 + q * 4 + r;
            if (j < JCN)
                tb[(size_t)j * HWN] = acc[tm][r] + b2[j];
        }
    }
}

// ---------------------------------------------------------------------------
// K2: depthwise deformable conv (round-0 verified geometry).
// NEW (a): y written as bf16 in MFMA B-fragment order — this thread's 8
// channels (chunk*8+cc) are exactly octet s=chunk>>2, q=chunk&3, j=cc, so the
// whole epilogue is ONE 16B store.  Halves y write traffic, and k_final's
// loads become two dwordx4.
// NEW (b): bijective XCD swizzle pairing chunks (2g, 2g+1) of the same tile
// adjacently on the same XCD -> the shared t planes (group g) are read once
// from HBM, hit L2 the second time.
// ---------------------------------------------------------------------------
__device__ __forceinline__ float dsample(const float* __restrict__ p, int yi, int xi) {
    if ((unsigned)yi < (unsigned)HN && (unsigned)xi < (unsigned)WN)
        return p[yi * WN + xi];
    return 0.f;
}

__global__ __launch_bounds__(256, 4) void k_deform(const float* __restrict__ x,
                                                   const float* __restrict__ t_in,
                                                   const float* __restrict__ wdef,
                                                   unsigned short* __restrict__ y_out) {
    __shared__ float xs[8 * XH * XW];                 // 22848 B
    __shared__ float wks[9 * 8];                      // [k][cc]
    __shared__ float wsums[8];

    // swizzle: 2304 blocks = 8 XCD * 288 slots; slot = (tile<<1)|cm;
    // XCD k runs zz = {2k, 2k+1} = both chunks of deform-group g=k%4, b=k/4.
    const int f    = blockIdx.x + 6 * blockIdx.y + 144 * blockIdx.z;  // 0..2303
    const int slot = f >> 3;
    const int xcd  = f & 7;
    const int tile = slot >> 1;
    const int cm   = slot & 1;
    const int zz   = 2 * xcd + cm;            // 0..15
    const int bx   = tile % 6;
    const int byy  = tile / 6;

    const int x0   = bx * SN;
    const int yr0  = byy * DROWS;
    const int b    = zz >> 3;
    const int chunk = zz & 7;                 // 8-channel chunk
    const int g    = chunk >> 1;              // deform group
    const int tid  = threadIdx.x;
    const int r    = tid >> 5;                // output row within tile
    const int px   = tid & 31;
    const int row_lo = yr0 - XRT;
    const int col_lo = x0 - XCL;
    const float* xb = x + (size_t)b * CN * HWN;

    // prefetch this thread's 18 offsets into registers (coalesced)
    float dyr[9], dxr[9];
    {
        const float* tbp = t_in + ((size_t)b * JCN + g * 18) * HWN
                         + (yr0 + r) * WN + x0 + px;
        #pragma unroll
        for (int k = 0; k < 9; ++k) {
            dyr[k] = tbp[(size_t)(2 * k) * HWN];
            dxr[k] = tbp[(size_t)(2 * k + 1) * HWN];
        }
    }

    // stage x window (zero-filled outside image)
    for (int idx = tid; idx < 8 * XH * XW; idx += 256) {
        int cc  = idx / (XH * XW);
        int rem = idx - cc * (XH * XW);
        int rr  = rem / XW;
        int col = rem - rr * XW;
        int yy  = row_lo + rr;
        int xx  = col_lo + col;
        float v = 0.f;
        if ((unsigned)yy < (unsigned)HN && (unsigned)xx < (unsigned)WN)
            v = xb[(size_t)(chunk * 8 + cc) * HWN + yy * WN + xx];
        xs[idx] = v;
    }
    // stage weights
    if (tid < 72) {
        int k = tid >> 3, cc = tid & 7;
        wks[tid] = wdef[(chunk * 8 + cc) * 9 + k];
    } else if (tid < 80) {
        int cc = tid - 72;
        float s = 0.f;
        #pragma unroll
        for (int k = 0; k < 9; ++k) s += wdef[(chunk * 8 + cc) * 9 + k];
        wsums[cc] = s;
    }
    __syncthreads();

    float acc[8];
    #pragma unroll
    for (int c = 0; c < 8; ++c)
        acc[c] = -xs[c * (XH * XW) + (XRT + r) * XW + XCL + px] * wsums[c];

    const float ry_basef = (float)(yr0 + r - 1);
    const float rx_basef = (float)(x0 + px - 1);

    #pragma unroll
    for (int k = 0; k < 9; ++k) {
        const int ky = k / 3, kx = k - 3 * ky;
        float py  = ry_basef + (float)ky + dyr[k];
        float pxf = rx_basef + (float)kx + dxr[k];
        float y0f = floorf(py), x0f = floorf(pxf);
        float wy = py - y0f, wx = pxf - x0f;
        int yi = (int)y0f, xi = (int)x0f;
        int ry = yi - row_lo, rx = xi - col_lo;
        float omwy = 1.f - wy, omwx = 1.f - wx;
        float w00 = omwy * omwx;
        float w01 = omwy * wx;
        float w10 = wy * omwx;
        float w11 = wy * wx;
        float4 wka = *(const float4*)&wks[k * 8];
        float4 wkb = *(const float4*)&wks[k * 8 + 4];
        float wkv[8] = {wka.x, wka.y, wka.z, wka.w, wkb.x, wkb.y, wkb.z, wkb.w};
        if ((unsigned)ry < (XH - 1) && (unsigned)rx < (XW - 1)) {
            const float* p0 = xs + ry * XW + rx;
            #pragma unroll
            for (int c = 0; c < 8; ++c) {
                const float* p = p0 + c * (XH * XW);
                float bil = p[0] * w00 + p[1] * w01 + p[XW] * w10 + p[XW + 1] * w11;
                acc[c] += wkv[c] * bil;
            }
        } else {
            #pragma unroll
            for (int c = 0; c < 8; ++c) {
                const float* xp = xb + (size_t)(chunk * 8 + c) * HWN;
                float v00 = dsample(xp, yi,     xi);
                float v01 = dsample(xp, yi,     xi + 1);
                float v10 = dsample(xp, yi + 1, xi);
                float v11 = dsample(xp, yi + 1, xi + 1);
                float bil = v00 * w00 + v01 * w01 + v10 * w10 + v11 * w11;
                acc[c] += wkv[c] * bil;
            }
        }
    }

    // bf16 B-frag store: y_bf[b][P][s][q][n][j], j contiguous (16B / thread)
    u16x8 pk;
    #pragma unroll
    for (int c = 0; c < 8; ++c) pk[c] = f2bf(acc[c]);
    const int P = (yr0 + r) * (WN / 16) + ((x0 + px) >> 4);
    unsigned short* yo = y_out
        + ((((size_t)b * PGRPS + P) * 2 + (chunk >> 2)) * 4 + (chunk & 3)) * 128
        + (px & 15) * 8;
    *(u16x8*)yo = pk;
}

// ---------------------------------------------------------------------------
// K3: m = w_out . y via MFMA.  y arrives bf16 in B-frag order: two 16B loads
// per thread replace 64 scalar plane-strided loads + 64 f2bf.
// ---------------------------------------------------------------------------
__global__ __launch_bounds__(256, 8) void k_final(const unsigned short* __restrict__ y_bf,
                                                  const unsigned short* __restrict__ womf,
                                                  float* __restrict__ m_out) {
    const int tid  = threadIdx.x;
    const int wv   = tid >> 6;
    const int lane = tid & 63;
    const int q    = lane >> 4;
    const int n    = lane & 15;
    const int yr   = blockIdx.y;
    const int b    = blockIdx.z;
    const int P    = yr * (WN / 16) + blockIdx.x * 4 + wv;

    const unsigned short* yp = y_bf + ((size_t)b * PGRPS + P) * 1024;
    bf16x8 bfr0 = *(const bf16x8*)(yp + (0 * 64 + q * 16 + n) * 8);
    bf16x8 bfr1 = *(const bf16x8*)(yp + (1 * 64 + q * 16 + n) * 8);

    const bf16x8* ap = (const bf16x8*)womf + lane;
    f32x4 acc[4];
    #pragma unroll
    for (int tm = 0; tm < 4; ++tm) acc[tm] = (f32x4){0.f, 0.f, 0.f, 0.f};
    #pragma unroll
    for (int tm = 0; tm < 4; ++tm) {
        acc[tm] = __builtin_amdgcn_mfma_f32_16x16x32_bf16(ap[(tm * 2 + 0) * 64], bfr0, acc[tm], 0, 0, 0);
        acc[tm] = __builtin_amdgcn_mfma_f32_16x16x32_bf16(ap[(tm * 2 + 1) * 64], bfr1, acc[tm], 0, 0, 0);
    }

    // D layout: col=lane&15, row=q*4+reg ; o = tm*16 + q*4 + r
    float* mb = m_out + (size_t)b * CN * HWN + yr * WN + blockIdx.x * 64 + wv * 16 + n;
    #pragma unroll
    for (int tm = 0; tm < 4; ++tm) {
        #pragma unroll
        for (int r = 0; r < 4; ++r)
            mb[(size_t)(tm * 16 + q * 4 + r) * HWN] = acc[tm][r];
    }
}

// ---------------------------------------------------------------------------
extern "C" void kernel_launch(void* const* d_in, const int* in_sizes, int n_in,
                              void* d_out, int out_size, void* d_ws, size_t ws_size,
                              hipStream_t stream) {
    const float* x1    = (const float*)d_in[0];   // 2*64*192*192
    const float* w_off1 = (const float*)d_in[1];  // 256*9
    const float* w_off2 = (const float*)d_in[2];  // 72*256
    const float* b_off2 = (const float*)d_in[3];  // 72
    const float* w_def = (const float*)d_in[4];   // 64*9
    const float* w_out = (const float*)d_in[5];   // 64*64

    float* out = (float*)d_out;
    const size_t n_x = (size_t)BN * CN * HWN;     // 4718592
    float* out_x1 = out;                          // output 0: x1 copy (fused into k_offsets)
    float* out_m  = out + n_x;                    // output 1: m

    // Workspace layout (bytes)
    char* ws0 = (char*)d_ws;
    unsigned short* w2mf   = (unsigned short*)ws0;            // 20480 bf16 = 40960 B
    unsigned short* w_outmf = (unsigned short*)(ws0 + 40960); // 4096 bf16 = 8192 B
    float* w1p    = (float*)(ws0 + 49152);                    // 2048 f = 8192 B
    float* t_ws   = (float*)(ws0 + 57344);                    // 2*72*36864 f = 21233664 B
    unsigned short* y_bf = (unsigned short*)(ws0 + 57344 + 21233664); // 2*2304*1024 u16 = 9.44 MB

    dim3 blk(256);

    k_prep<<<dim3(104), blk, 0, stream>>>(w_off2, w_out, w_off1, w2mf, w_outmf, w1p);
    k_offsets<<<dim3(WN / 64, HN, BN), blk, 0, stream>>>(x1, w1p, w2mf, b_off2,
                                                         t_ws, out_x1);
    k_deform<<<dim3(WN / SN, HN / DROWS, BN * 8), blk, 0, stream>>>(x1, t_ws, w_def, y_bf);
    k_final<<<dim3(WN / 64, HN, BN), blk, 0, stream>>>(y_bf, w_outmf, out_m);
}